// Round 10
// baseline (38.334 us; speedup 1.0000x reference)
//
#include <hip/hip_runtime.h>

#define DENSE_L 20
#define LT 16
#define BLOCK 256
#define KQ 4                   // k-outputs per quarter pass
#define NPASS (LT / KQ)        // 4
#define GPP (DENSE_L * KQ)     // 80 G floats per pass = 5 x 64B uniform loads
#define TILE (BLOCK * DENSE_L) // 5120 dwords = 20 KB per tile

typedef float v4f  __attribute__((ext_vector_type(4)));
typedef float v16f __attribute__((ext_vector_type(16)));

// Precompute G transposed: Gt[k*20 + t] = exp(-((t+1)-w_k)^2 / std^2).
__global__ void g_precompute(const float* __restrict__ weight, float* __restrict__ Gt)
{
    int i = threadIdx.x;               // 320 threads
    if (i < DENSE_L * LT) {
        int k = i / DENSE_L;
        int t = i - k * DENSE_L;
        float d = (float)(t + 1) - weight[k];
        Gt[i] = __expf(-d * d * 6.25f);    // 1/std^2 = 6.25
    }
}

// Direct global->LDS DMA, 16B/lane; dest is lane-linear (wave-uniform base + lane*16).
__device__ __forceinline__ void async_copy16(const float* g, float* l)
{
    __builtin_amdgcn_global_load_lds(
        (const __attribute__((address_space(1))) void*)g,
        (__attribute__((address_space(3))) void*)l,
        16, 0, 0);
}

// One tile: read own row from buf, 4 SGPR-G quarter passes, out-stage ALIASED
// into buf (thread t's 16 outputs overwrite its own 20-float x row -> thread-
// private, no barrier needed between compute and os-write), then coalesced store.
__device__ __forceinline__ void process_tile(
    float* buf, const float* __restrict__ Gt, float4* po, int tid)
{
    float xv[DENSE_L];
    #pragma unroll
    for (int j = 0; j < 5; ++j) {      // 5 x ds_read_b128, 80B stride = 2-way = free
        float4 v = *reinterpret_cast<const float4*>(&buf[tid * DENSE_L + 4 * j]);
        xv[4*j+0] = v.x; xv[4*j+1] = v.y; xv[4*j+2] = v.z; xv[4*j+3] = v.w;
    }

    #pragma unroll 1                   // rolled: one quarter's 80 G SGPRs live at a time
    for (int p = 0; p < NPASS; ++p) {
        const v16f* gq = reinterpret_cast<const v16f*>(Gt + p * GPP);
        v16f q[5] = {gq[0], gq[1], gq[2], gq[3], gq[4]};   // s_load_dwordx16 x5

        float a[KQ] = {0.f, 0.f, 0.f, 0.f};
        #pragma unroll
        for (int kk = 0; kk < KQ; ++kk) {
            #pragma unroll
            for (int t = 0; t < DENSE_L; ++t) {
                int gi = kk * DENSE_L + t;            // compile-time after unroll
                a[kk] += xv[t] * q[gi >> 4][gi & 15]; // v_fmac v,s,v
            }
        }
        // out-stage into own x row (dwords 20*tid+4p .. +3; 16B aligned)
        *reinterpret_cast<v4f*>(&buf[tid * DENSE_L + 4 * p]) = (v4f){a[0], a[1], a[2], a[3]};
    }
    __syncthreads();                   // os visible to all before cross-thread store sweep

    #pragma unroll
    for (int j = 0; j < 4; ++j) {      // coalesced full-line stores
        int g = tid + BLOCK * j;
        int r = g >> 2, s = g & 3;
        po[g] = *reinterpret_cast<const float4*>(&buf[r * DENSE_L + 4 * s]);
    }
}

// R10: two tiles per block, all 10 direct-to-LDS loads issued in ONE prologue ->
// a single vmcnt(0) drain serves both tiles (R8/R9 paid one full drain per tile).
// Tile1 computes with zero load-wait; tile0's stores overlap tile1's compute.
// 40KB LDS keeps 4 blocks/CU. Frozen: SGPR-G quarters (R6), coalesced staged I/O
// (R8), regular stores (NT amp 1.8x R4/R7), no min-waves hints (R2/R3 spills).
__global__ __launch_bounds__(BLOCK) void sampling_kernel(
    const float* __restrict__ x, const float* __restrict__ Gt,
    float* __restrict__ out, int nrows)
{
    __shared__ float xs0[TILE];
    __shared__ float xs1[TILE];

    const int tid = threadIdx.x;
    const size_t row0 = (size_t)blockIdx.x * (2 * BLOCK);
    const float* src = x + row0 * DENSE_L;

    #pragma unroll
    for (int j = 0; j < 5; ++j) {
        int f = tid + BLOCK * j;
        async_copy16(src + 4 * f, xs0 + 4 * f);
    }
    #pragma unroll
    for (int j = 0; j < 5; ++j) {
        int f = tid + BLOCK * j;
        async_copy16(src + TILE + 4 * f, xs1 + 4 * f);
    }
    __syncthreads();   // single vmcnt(0) drain for both tiles

    float4* po = reinterpret_cast<float4*>(out + row0 * LT);
    process_tile(xs0, Gt, po, tid);
    // no barrier: tile1 reads xs1 (untouched); tile0's store phase reads xs0 only
    process_tile(xs1, Gt, po + (BLOCK * LT) / 4, tid);
}

extern "C" void kernel_launch(void* const* d_in, const int* in_sizes, int n_in,
                              void* d_out, int out_size, void* d_ws, size_t ws_size,
                              hipStream_t stream) {
    const float* x = (const float*)d_in[0];
    const float* w = (const float*)d_in[1];
    float* out = (float*)d_out;
    float* Gt = (float*)d_ws;                // 320 floats = 1280 B workspace
    int nrows = in_sizes[0] / DENSE_L;       // 1,048,576 (divisible by 512)

    g_precompute<<<1, 320, 0, stream>>>(w, Gt);

    int grid = nrows / (2 * BLOCK);          // 2048 blocks, 512 rows each
    sampling_kernel<<<grid, BLOCK, 0, stream>>>(x, Gt, out, nrows);
}

// Round 11
// 36.127 us; speedup vs baseline: 1.0611x; 1.0611x over previous
//
#include <hip/hip_runtime.h>

#define DENSE_L 20
#define LT 16
#define BLOCK 256
#define KQ 4                   // k-outputs per quarter pass
#define NPASS (LT / KQ)        // 4
#define GPP (DENSE_L * KQ)     // 80 G floats per pass = 5 x 64B uniform loads
#define TILE (BLOCK * DENSE_L) // 5120 dwords = 20 KB

typedef float v4f  __attribute__((ext_vector_type(4)));
typedef float v16f __attribute__((ext_vector_type(16)));

// Precompute G transposed: Gt[k*20 + t] = exp(-((t+1)-w_k)^2 / std^2).
__global__ void g_precompute(const float* __restrict__ weight, float* __restrict__ Gt)
{
    int i = threadIdx.x;               // 320 threads
    if (i < DENSE_L * LT) {
        int k = i / DENSE_L;
        int t = i - k * DENSE_L;
        float d = (float)(t + 1) - weight[k];
        Gt[i] = __expf(-d * d * 6.25f);    // 1/std^2 = 6.25
    }
}

// Direct global->LDS DMA, 16B/lane; dest is lane-linear (wave-uniform base + lane*16).
__device__ __forceinline__ void async_copy16(const float* g, float* l)
{
    __builtin_amdgcn_global_load_lds(
        (const __attribute__((address_space(1))) void*)g,
        (__attribute__((address_space(3))) void*)l,
        16, 0, 0);
}

// R11: R9's proven one-tile pipeline + R10's proven-safe out-stage aliasing
// (thread t's 16 outputs overwrite its OWN 20-float x row -> thread-private,
// no extra barrier) -> LDS 40KB->20KB -> 8 blocks/CU resident (was 4).
// Rationale: R9/R10 showed the drain is hidden by OTHER resident blocks at
// different phases (m114 overlap), and R10's longer serial chain regressed;
// so feed the hiding mechanism directly: 2x resident blocks, same chain.
// Frozen: SGPR-G rolled quarters (R6), global_load_lds staging (R9),
// coalesced full-line regular stores (R0/R8; NT amplified 1.8x R4/R7),
// no launch_bounds min-waves hints (R2/R3 spills).
__global__ __launch_bounds__(BLOCK) void sampling_kernel(
    const float* __restrict__ x, const float* __restrict__ Gt,
    float* __restrict__ out, int nrows)
{
    __shared__ float buf[TILE];        // 20 KB: x stage, then (aliased) out stage

    const int tid = threadIdx.x;
    const size_t blockRow = (size_t)blockIdx.x * BLOCK;

    // ---- coalesced x load, direct to LDS: 5 x global_load_lds_dwordx4 ----
    {
        const float* src = x + blockRow * DENSE_L;
        #pragma unroll
        for (int j = 0; j < 5; ++j) {
            int f = tid + BLOCK * j;            // float4 index in 20KB tile
            async_copy16(src + 4 * f, buf + 4 * f);
        }
    }
    __syncthreads();   // vmcnt(0) drain + barrier (hidden by 7 other resident blocks)

    // ---- each thread pulls its own row (5 x ds_read_b128, 80B stride = 2-way = free) ----
    float xv[DENSE_L];
    #pragma unroll
    for (int j = 0; j < 5; ++j) {
        float4 v = *reinterpret_cast<const float4*>(&buf[tid * DENSE_L + 4 * j]);
        xv[4*j+0] = v.x; xv[4*j+1] = v.y; xv[4*j+2] = v.z; xv[4*j+3] = v.w;
    }
    // no barrier: out-stage writes go to this thread's own row only

    // ---- 4 rolled k-quarter passes; G uniform-loaded into SGPRs ----
    #pragma unroll 1                   // rolled: one quarter's 80 G SGPRs live at a time
    for (int p = 0; p < NPASS; ++p) {
        const v16f* gq = reinterpret_cast<const v16f*>(Gt + p * GPP);
        v16f q[5] = {gq[0], gq[1], gq[2], gq[3], gq[4]};   // 5 x s_load_dwordx16

        float a[KQ] = {0.f, 0.f, 0.f, 0.f};
        #pragma unroll
        for (int kk = 0; kk < KQ; ++kk) {
            #pragma unroll
            for (int t = 0; t < DENSE_L; ++t) {
                int gi = kk * DENSE_L + t;            // compile-time after unroll
                a[kk] += xv[t] * q[gi >> 4][gi & 15]; // v_fmac v,s,v
            }
        }
        // out-stage aliased into own x row (dwords 20*tid + 4p..+3, 16B aligned)
        *reinterpret_cast<v4f*>(&buf[tid * DENSE_L + 4 * p]) = (v4f){a[0], a[1], a[2], a[3]};
    }
    __syncthreads();   // out-stage visible before cross-thread store sweep

    // ---- coalesced out store: full 64B lines, regular stores ----
    {
        float4* po = reinterpret_cast<float4*>(out + blockRow * LT);
        #pragma unroll
        for (int j = 0; j < 4; ++j) {
            int g = tid + BLOCK * j;                 // global float4 index in tile
            int r = g >> 2, s = g & 3;               // out row / sub-quad
            po[g] = *reinterpret_cast<const float4*>(&buf[r * DENSE_L + 4 * s]);
        }
    }
}

extern "C" void kernel_launch(void* const* d_in, const int* in_sizes, int n_in,
                              void* d_out, int out_size, void* d_ws, size_t ws_size,
                              hipStream_t stream) {
    const float* x = (const float*)d_in[0];
    const float* w = (const float*)d_in[1];
    float* out = (float*)d_out;
    float* Gt = (float*)d_ws;                // 320 floats = 1280 B workspace
    int nrows = in_sizes[0] / DENSE_L;       // 1,048,576 (divisible by 256)

    g_precompute<<<1, 320, 0, stream>>>(w, Gt);

    int grid = nrows / BLOCK;                // 4096 blocks, one 256-row tile each
    sampling_kernel<<<grid, BLOCK, 0, stream>>>(x, Gt, out, nrows);
}

// Round 12
// 35.754 us; speedup vs baseline: 1.0722x; 1.0104x over previous
//
#include <hip/hip_runtime.h>

#define DENSE_L 20
#define LT 16
#define BLOCK 256
#define KQ 4                   // k-outputs per quarter pass
#define NPASS (LT / KQ)        // 4
#define GPP (DENSE_L * KQ)     // 80 G floats per pass = 5 x 64B uniform loads
#define OPAD 20                // padded out-stage row (dwords): 2-way banks, 16B-aligned

typedef float v4f  __attribute__((ext_vector_type(4)));
typedef float v16f __attribute__((ext_vector_type(16)));

// Precompute G transposed: Gt[k*20 + t] = exp(-((t+1)-w_k)^2 / std^2).
__global__ void g_precompute(const float* __restrict__ weight, float* __restrict__ Gt)
{
    int i = threadIdx.x;               // 320 threads
    if (i < DENSE_L * LT) {
        int k = i / DENSE_L;
        int t = i - k * DENSE_L;
        float d = (float)(t + 1) - weight[k];
        Gt[i] = __expf(-d * d * 6.25f);    // 1/std^2 = 6.25
    }
}

// FINAL (revert to R8, best measured: 35.49us). 12-round evidence summary:
//  - The one structural win: stage x through LDS so global loads are perfectly
//    coalesced (R8: 50->35.5us). The 80B per-lane stride was the floor-setter.
//  - SGPR-G rolled quarters: G is wave-uniform; uniform loads of the
//    precomputed table scalarize (SGPR ~96), freeing VGPRs + deleting LDS
//    G-traffic (R6).
//  - Neutral: global_load_lds DMA (R9), barrier removal (R9), 8 blocks/CU (R11).
//  - Harmful: NT stores (1.8x write amp, R4/R7), min-waves hints (spill, R2/R3),
//    2-tile serial chains (R10), chunked x streaming (HBM re-fetch, R4/R5).
//  - Occupancy 8->56% never mattered: limiter is mixed-stream BW (~24-26us for
//    151MB) + precompute dispatch serialization (~4-6us) + head/tail latency.
__global__ __launch_bounds__(BLOCK) void sampling_kernel(
    const float* __restrict__ x, const float* __restrict__ Gt,
    float* __restrict__ out, int nrows)
{
    __shared__ float lds[BLOCK * DENSE_L];   // 20 KB: x stage, then out stage

    const int tid = threadIdx.x;
    const size_t blockRow = (size_t)blockIdx.x * BLOCK;

    // ---- coalesced x load: 1280 float4s, lane i -> float4 i (+256j) ----
    {
        const float4* px = reinterpret_cast<const float4*>(x + blockRow * DENSE_L);
        #pragma unroll
        for (int j = 0; j < 5; ++j) {
            int f = tid + BLOCK * j;                 // float4 index in block tile
            float4 v = px[f];
            *reinterpret_cast<float4*>(&lds[4 * f]) = v;   // linear LDS, 16B aligned
        }
    }
    __syncthreads();

    // ---- each thread pulls its own row from LDS (5 x ds_read_b128, 2-way) ----
    float xv[DENSE_L];
    {
        #pragma unroll
        for (int j = 0; j < 5; ++j) {
            float4 v = *reinterpret_cast<const float4*>(&lds[tid * DENSE_L + 4 * j]);
            xv[4*j+0] = v.x; xv[4*j+1] = v.y; xv[4*j+2] = v.z; xv[4*j+3] = v.w;
        }
    }
    __syncthreads();   // all row-reads done before out-stage overwrites lds

    // ---- 4 rolled k-quarter passes; G uniform-loaded into SGPRs (R6-proven) ----
    #pragma unroll 1
    for (int p = 0; p < NPASS; ++p) {
        const v16f* gq = reinterpret_cast<const v16f*>(Gt + p * GPP);
        v16f q[5] = {gq[0], gq[1], gq[2], gq[3], gq[4]};

        float a[KQ] = {0.f, 0.f, 0.f, 0.f};
        #pragma unroll
        for (int kk = 0; kk < KQ; ++kk) {
            #pragma unroll
            for (int t = 0; t < DENSE_L; ++t) {
                int gi = kk * DENSE_L + t;            // compile-time after unroll
                a[kk] += xv[t] * q[gi >> 4][gi & 15]; // v_fmac v,s,v
            }
        }
        // stage quarter into LDS: row tid, padded stride 20 dwords (2-way banks)
        *reinterpret_cast<v4f*>(&lds[tid * OPAD + 4 * p]) = (v4f){a[0], a[1], a[2], a[3]};
    }
    __syncthreads();

    // ---- coalesced out store: full 64B lines, regular stores ----
    {
        float4* po = reinterpret_cast<float4*>(out + blockRow * LT);
        #pragma unroll
        for (int j = 0; j < 4; ++j) {
            int g = tid + BLOCK * j;                 // global float4 index in tile
            int r = g >> 2, s = g & 3;               // out row / sub-quad
            float4 v = *reinterpret_cast<const float4*>(&lds[r * OPAD + 4 * s]);
            po[g] = v;
        }
    }
}

extern "C" void kernel_launch(void* const* d_in, const int* in_sizes, int n_in,
                              void* d_out, int out_size, void* d_ws, size_t ws_size,
                              hipStream_t stream) {
    const float* x = (const float*)d_in[0];
    const float* w = (const float*)d_in[1];
    float* out = (float*)d_out;
    float* Gt = (float*)d_ws;                // 320 floats = 1280 B workspace
    int nrows = in_sizes[0] / DENSE_L;       // 1,048,576 (divisible by 256)

    g_precompute<<<1, 320, 0, stream>>>(w, Gt);

    int grid = nrows / BLOCK;                // 4096 full blocks
    sampling_kernel<<<grid, BLOCK, 0, stream>>>(x, Gt, out, nrows);
}